// Round 3
// baseline (2565.273 us; speedup 1.0000x reference)
//
#include <hip/hip_runtime.h>
#include <stdint.h>

#define NUM_TOTAL 150000
#define NUM_USER  50000
#define NUM_ITEM  100000
#define E_SOC 1600000
#define E_CO  3200000
#define BATCH 512
#define MAX_UI 64
#define MAX_IU 50
#define NWALK 96
#define NCAND 11
#define MASKW 3125   // 100000/32

// 1 = modern JAX (jax_threefry_partitionable=True): counter = (hi,lo) of u64
//     linear index, bits = out0 ^ out1.
// 0 = legacy: iota split in halves; first half -> out0 with ctr (j, j+H),
//     second half -> out1 with ctr (j-H, j), H = 25,600,000.
#define TF_PARTITIONABLE 1

// ---------------- threefry2x32, key = (0, 42) ----------------
__device__ __forceinline__ uint32_t rotl32(uint32_t x, int r){ return (x<<r)|(x>>(32-r)); }

__device__ __forceinline__ void tf_core(uint32_t x0, uint32_t x1, uint32_t& o0, uint32_t& o1){
  const uint32_t k0 = 0u, k1 = 42u, k2 = 0u ^ 42u ^ 0x1BD11BDAu;
  x0 += k0; x1 += k1;
#define TF_R4(a,b,c,d) \
  x0+=x1; x1=rotl32(x1,a); x1^=x0; \
  x0+=x1; x1=rotl32(x1,b); x1^=x0; \
  x0+=x1; x1=rotl32(x1,c); x1^=x0; \
  x0+=x1; x1=rotl32(x1,d); x1^=x0;
  TF_R4(13,15,26,6)   x0+=k1; x1+=k2+1u;
  TF_R4(17,29,16,24)  x0+=k2; x1+=k0+2u;
  TF_R4(13,15,26,6)   x0+=k0; x1+=k1+3u;
  TF_R4(17,29,16,24)  x0+=k1; x1+=k2+4u;
  TF_R4(13,15,26,6)   x0+=k2; x1+=k0+5u;
#undef TF_R4
  o0 = x0; o1 = x1;
}

__device__ __forceinline__ uint32_t tf_bits(uint32_t j){
#if TF_PARTITIONABLE
  uint32_t o0, o1;
  tf_core(0u, j, o0, o1);          // hi(j)=0 for j < 2^32
  return o0 ^ o1;
#else
  const uint32_t H = 25600000u;    // (512*100000)/2
  uint32_t o0, o1;
  if (j < H){ tf_core(j, j + H, o0, o1); return o0; }
  else      { tf_core(j - H, j, o0, o1); return o1; }
#endif
}

// ---------------- small utility kernels ----------------
__global__ void zero_i32(int* __restrict__ p, int n){
  int i = blockIdx.x*blockDim.x + threadIdx.x, st = gridDim.x*blockDim.x;
  for (; i<n; i+=st) p[i] = 0;
}

__global__ void hist_k(const int* __restrict__ dst, int E, int* __restrict__ cnt){
  int i = blockIdx.x*blockDim.x + threadIdx.x, st = gridDim.x*blockDim.x;
  for (; i<E; i+=st) atomicAdd(&cnt[dst[i]], 1);
}

// single-block exclusive scan: per-thread contiguous chunk + Hillis-Steele on partials
__global__ __launch_bounds__(1024) void exscan_k(const int* __restrict__ cnt, int n, int* __restrict__ off){
  __shared__ int part[1024];
  int tid = threadIdx.x;
  int chunk = (n + 1023) >> 10;
  int lo = tid*chunk;
  int hi = lo + chunk; if (hi > n) hi = n;
  int s = 0;
  for (int i=lo; i<hi; ++i) s += cnt[i];
  part[tid] = s; __syncthreads();
  for (int st=1; st<1024; st<<=1){
    int t = (tid>=st) ? part[tid-st] : 0;
    __syncthreads();
    part[tid] += t;
    __syncthreads();
  }
  int base = part[tid] - s;
  for (int i=lo; i<hi; ++i){ off[i] = base; base += cnt[i]; }
  if (tid == 1023) off[n] = part[1023];
}

__global__ void scatter_soc_k(const int* __restrict__ src, const int* __restrict__ dst,
                              const float* __restrict__ w, const int* __restrict__ off,
                              int* __restrict__ cur, int* __restrict__ srcS,
                              float* __restrict__ wS, int E){
  int i = blockIdx.x*blockDim.x + threadIdx.x, st = gridDim.x*blockDim.x;
  for (; i<E; i+=st){
    int d = dst[i];
    int p = off[d] + atomicAdd(&cur[d], 1);
    srcS[p] = src[i];
    wS[p]   = w[i];
  }
}

__global__ void scatter_co_k(const int* __restrict__ src, const int* __restrict__ dst,
                             const int* __restrict__ off, int* __restrict__ cur,
                             int* __restrict__ srcS, int E){
  int i = blockIdx.x*blockDim.x + threadIdx.x, st = gridDim.x*blockDim.x;
  for (; i<E; i+=st){
    int d = dst[i];
    int p = off[d] + atomicAdd(&cur[d], 1);
    srcS[p] = src[i];
  }
}

__global__ void dinv_k(const int* __restrict__ cnt, float* __restrict__ dinv, int n){
  int i = blockIdx.x*blockDim.x + threadIdx.x, st = gridDim.x*blockDim.x;
  for (; i<n; i+=st) dinv[i] = 1.0f / sqrtf((float)(cnt[i] + 1));   // deg = in-deg + self loop
}

// per-node softmax over incoming edge weights -> alpha (in place over wS)
__global__ void alpha_k(const int* __restrict__ off, float* __restrict__ wS, int n){
  int v = blockIdx.x*blockDim.x + threadIdx.x;
  if (v >= n) return;
  int e0 = off[v], e1 = off[v+1];
  if (e0 == e1) return;
  float m = -3.402823466e+38f;
  for (int e=e0; e<e1; ++e) m = fmaxf(m, wS[e]);
  float s = 0.f;
  for (int e=e0; e<e1; ++e) s += expf(wS[e] - m);
  float inv = 1.0f / (s + 1e-16f);
  for (int e=e0; e<e1; ++e) wS[e] = expf(wS[e] - m) * inv;
}

// ---------------- aggregation: one wave per dst node, float2 per lane ----------------
__global__ void agg_soc_k(const float* __restrict__ x, float* __restrict__ y,
                          const int* __restrict__ off, const int* __restrict__ srcS,
                          const float* __restrict__ alphaS, int n){
  int gw = (blockIdx.x*blockDim.x + threadIdx.x) >> 6;
  int lane = threadIdx.x & 63;
  if (gw >= n) return;
  float ax = 0.f, ay = 0.f;
  int e1 = off[gw+1];
  for (int e = off[gw]; e < e1; ++e){
    int s = srcS[e];
    float a = alphaS[e];
    float2 r = ((const float2*)x)[(size_t)s*64 + lane];
    ax += a*r.x; ay += a*r.y;
  }
  ((float2*)y)[(size_t)gw*64 + lane] = make_float2(ax, ay);
}

__global__ void agg_co_k(const float* __restrict__ x, float* __restrict__ y,
                         const int* __restrict__ off, const int* __restrict__ srcS,
                         const float* __restrict__ dinv, int n){
  int gw = (blockIdx.x*blockDim.x + threadIdx.x) >> 6;
  int lane = threadIdx.x & 63;
  if (gw >= n) return;
  float dv = dinv[gw];
  float2 self = ((const float2*)x)[(size_t)gw*64 + lane];
  float ax = dv*dv*self.x, ay = dv*dv*self.y;     // self-loop term
  int e1 = off[gw+1];
  for (int e = off[gw]; e < e1; ++e){
    int s = srcS[e];
    float a = dinv[s]*dv;
    float2 r = ((const float2*)x)[(size_t)s*64 + lane];
    ax += a*r.x; ay += a*r.y;
  }
  ((float2*)y)[(size_t)gw*64 + lane] = make_float2(ax, ay);
}

// L2-normalize rows in place (wave per row)
__global__ void norm_rows_k(float* __restrict__ x, int n){
  int gw = (blockIdx.x*blockDim.x + threadIdx.x) >> 6;
  int lane = threadIdx.x & 63;
  if (gw >= n) return;
  float2* p = (float2*)x + (size_t)gw*64;
  float2 v = p[lane];
  float ss = v.x*v.x + v.y*v.y;
  #pragma unroll
  for (int s=32; s; s>>=1) ss += __shfl_xor(ss, s, 64);
  float sc = 1.0f / fmaxf(sqrtf(ss), 1e-12f);
  p[lane] = make_float2(v.x*sc, v.y*sc);
}

// anchor = mean of 50 user rows, then L2-normalize; wave per item
__global__ void anchor_k(const float* __restrict__ soc, const int* __restrict__ item_users,
                         float* __restrict__ outI, int n){
  int gw = (blockIdx.x*blockDim.x + threadIdx.x) >> 6;
  int lane = threadIdx.x & 63;
  if (gw >= n) return;
  const int* us = item_users + (size_t)gw*MAX_IU;
  float ax = 0.f, ay = 0.f;
  for (int k=0; k<MAX_IU; ++k){
    int u = us[k];
    float2 r = ((const float2*)soc)[(size_t)u*64 + lane];
    ax += r.x; ay += r.y;
  }
  const float inv = 1.0f / (50.0f + 1e-7f);
  ax *= inv; ay *= inv;
  float ss = ax*ax + ay*ay;
  #pragma unroll
  for (int s=32; s; s>>=1) ss += __shfl_xor(ss, s, 64);
  float sc = 1.0f / fmaxf(sqrtf(ss), 1e-12f);
  ((float2*)outI)[(size_t)gw*64 + lane] = make_float2(ax*sc, ay*sc);
}

// ---------------- top-k negative sampling (block per batch row) ----------------
__global__ __launch_bounds__(256) void topk_k(const int* __restrict__ user_items,
                                              const int* __restrict__ n_id,
                                              int* __restrict__ cand){
  __shared__ unsigned int mask[MASKW];
  __shared__ unsigned long long pool[2560];
  __shared__ unsigned long long red[256];
  int b = blockIdx.x, tid = threadIdx.x;
  for (int i=tid; i<MASKW; i+=256) mask[i] = 0u;
  __syncthreads();
  if (tid < MAX_UI){
    int it = user_items[b*MAX_UI + tid];
    if (it >= 0) atomicOr(&mask[it>>5], 1u << (it & 31));
  }
  __syncthreads();

  unsigned long long best[10];
  #pragma unroll
  for (int k=0; k<10; ++k) best[k] = 0ull;

  unsigned int jbase = (unsigned int)b * 100000u;
  for (int i=tid; i<NUM_ITEM; i+=256){
    if ((mask[i>>5] >> (i & 31)) & 1u) continue;     // excluded item -> score -1
    unsigned int bits = tf_bits(jbase + (unsigned int)i);
    unsigned int v = bits >> 9;                       // monotone with uniform float
    unsigned long long key = ((unsigned long long)v << 32) | (unsigned int)(~(unsigned int)i);
    if (key > best[9]){
      best[9] = key;
      #pragma unroll
      for (int r=9; r>0; --r)
        if (best[r] > best[r-1]){ unsigned long long t = best[r-1]; best[r-1] = best[r]; best[r] = t; }
    }
  }
  #pragma unroll
  for (int k=0; k<10; ++k) pool[tid*10 + k] = best[k];
  __syncthreads();

  for (int r=0; r<10; ++r){
    unsigned long long m = 0ull;
    #pragma unroll
    for (int k=0; k<10; ++k){ unsigned long long p = pool[tid*10 + k]; if (p > m) m = p; }
    red[tid] = m; __syncthreads();
    for (int s=128; s>0; s>>=1){
      if (tid < s && red[tid+s] > red[tid]) red[tid] = red[tid+s];
      __syncthreads();
    }
    unsigned long long win = red[0];
    if (tid == 0)
      cand[b*NCAND + 1 + r] = NUM_USER + (int)(~(unsigned int)(win & 0xffffffffull));
    #pragma unroll
    for (int k=0; k<10; ++k) if (pool[tid*10 + k] == win) pool[tid*10 + k] = 0ull;
    __syncthreads();
  }
  if (tid == 0) cand[b*NCAND] = n_id[b*2 + 1];   // positive item (global id)
}

// ---------------- similarity (mean over walks collapses to one dot) ----------------
__global__ void sim_k(const float* __restrict__ coN, const float* __restrict__ socU,
                      const float* __restrict__ socI, const int* __restrict__ cand,
                      const int* __restrict__ walks, float* __restrict__ out){
  int b = blockIdx.x;
  int lane = threadIdx.x;   // 64 threads
  const float2* co2 = (const float2*)coN;
  const float2* su2 = (const float2*)socU;
  const float2* si2 = (const float2*)socI;
  float scx=0.f, scy=0.f, ssx=0.f, ssy=0.f;
  for (int w=0; w<NWALK; ++w){
    int idx = walks[b*NWALK + w];
    float2 c = co2[(size_t)idx*64 + lane];
    scx += c.x; scy += c.y;
    float2 s = (idx < NUM_USER) ? su2[(size_t)idx*64 + lane]
                                : si2[(size_t)(idx - NUM_USER)*64 + lane];
    ssx += s.x; ssy += s.y;
  }
  for (int c=0; c<NCAND; ++c){
    int idx = cand[b*NCAND + c];                 // always in [NUM_USER, NUM_TOTAL)
    float2 cv = co2[(size_t)idx*64 + lane];
    float2 sv = si2[(size_t)(idx - NUM_USER)*64 + lane];
    float dco = cv.x*scx + cv.y*scy;
    float dso = sv.x*ssx + sv.y*ssy;
    #pragma unroll
    for (int s=32; s; s>>=1){
      dco += __shfl_xor(dco, s, 64);
      dso += __shfl_xor(dso, s, 64);
    }
    if (lane == 0){
      float com = 0.5f + 0.5f*(dco / 96.0f);
      float som = 0.5f + 0.5f*(dso / 96.0f);
      out[b*NCAND + c] = 0.7f*com + 0.3f*som;
    }
  }
}

// ---------------- host ----------------
extern "C" void kernel_launch(void* const* d_in, const int* in_sizes, int n_in,
                              void* d_out, int out_size, void* d_ws, size_t ws_size,
                              hipStream_t stream){
  (void)in_sizes; (void)n_in; (void)out_size; (void)ws_size;
  const float* id_emb     = (const float*)d_in[0];
  const float* soc_id_emb = (const float*)d_in[1];
  const float* soc_w      = (const float*)d_in[2];
  const int*   soc_ei     = (const int*)d_in[3];   // [0:E) src, [E:2E) dst
  const int*   co_ei      = (const int*)d_in[4];
  const int*   n_id       = (const int*)d_in[5];
  const int*   user_items = (const int*)d_in[6];
  const int*   item_users = (const int*)d_in[7];
  const int*   walks      = (const int*)d_in[8];
  float* out = (float*)d_out;

  // workspace layout (~260 MB)
  char* w = (char*)d_ws;
  size_t cur = 0;
  auto take = [&](size_t bytes)->void*{
    void* p = w + cur;
    cur = (cur + bytes + 255) & ~(size_t)255;
    return p;
  };
  float* bufSoc  = (float*)take((size_t)NUM_TOTAL*128*4);  // soc_emb; user rows normalized later
  float* bufCo   = (float*)take((size_t)NUM_TOTAL*128*4);  // co_emb -> co_n in place
  float* bufA    = (float*)take((size_t)NUM_TOTAL*128*4);  // ping buffer, then normalized anchors
  int*   socOff  = (int*)take((size_t)(NUM_TOTAL+1)*4);
  int*   coOff   = (int*)take((size_t)(NUM_TOTAL+1)*4);
  int*   cntS    = (int*)take((size_t)NUM_TOTAL*4);
  int*   cntC    = (int*)take((size_t)NUM_TOTAL*4);
  int*   cur2    = (int*)take((size_t)NUM_TOTAL*4);
  float* dinv    = (float*)take((size_t)NUM_TOTAL*4);
  int*   socSrcS = (int*)take((size_t)E_SOC*4);
  float* socWS   = (float*)take((size_t)E_SOC*4);
  int*   coSrcS  = (int*)take((size_t)E_CO*4);
  int*   cand    = (int*)take((size_t)BATCH*NCAND*4);

  const int T = 256;
  // CSC build
  zero_i32<<<512, T, 0, stream>>>(cntS, NUM_TOTAL);
  zero_i32<<<512, T, 0, stream>>>(cntC, NUM_TOTAL);
  hist_k<<<2048, T, 0, stream>>>(soc_ei + E_SOC, E_SOC, cntS);
  hist_k<<<2048, T, 0, stream>>>(co_ei + E_CO,  E_CO,  cntC);
  exscan_k<<<1, 1024, 0, stream>>>(cntS, NUM_TOTAL, socOff);
  exscan_k<<<1, 1024, 0, stream>>>(cntC, NUM_TOTAL, coOff);
  zero_i32<<<512, T, 0, stream>>>(cur2, NUM_TOTAL);
  scatter_soc_k<<<2048, T, 0, stream>>>(soc_ei, soc_ei + E_SOC, soc_w, socOff, cur2, socSrcS, socWS, E_SOC);
  zero_i32<<<512, T, 0, stream>>>(cur2, NUM_TOTAL);
  scatter_co_k<<<2048, T, 0, stream>>>(co_ei, co_ei + E_CO, coOff, cur2, coSrcS, E_CO);

  dinv_k<<<(NUM_TOTAL + T - 1)/T, T, 0, stream>>>(cntC, dinv, NUM_TOTAL);
  alpha_k<<<(NUM_TOTAL + T - 1)/T, T, 0, stream>>>(socOff, socWS, NUM_TOTAL);

  // graph convolutions (wave per node)
  int aggGrid = (NUM_TOTAL + 3) / 4;
  agg_soc_k<<<aggGrid, T, 0, stream>>>(soc_id_emb, bufA,  socOff, socSrcS, socWS, NUM_TOTAL);
  agg_soc_k<<<aggGrid, T, 0, stream>>>(bufA,       bufSoc, socOff, socSrcS, socWS, NUM_TOTAL);
  agg_co_k <<<aggGrid, T, 0, stream>>>(id_emb,     bufA,  coOff,  coSrcS,  dinv,  NUM_TOTAL);
  agg_co_k <<<aggGrid, T, 0, stream>>>(bufA,       bufCo, coOff,  coSrcS,  dinv,  NUM_TOTAL);

  // normalizations / anchors
  norm_rows_k<<<aggGrid, T, 0, stream>>>(bufCo, NUM_TOTAL);                    // co_n
  anchor_k<<<(NUM_ITEM + 3)/4, T, 0, stream>>>(bufSoc, item_users, bufA, NUM_ITEM); // soc_n items
  norm_rows_k<<<(NUM_USER + 3)/4, T, 0, stream>>>(bufSoc, NUM_USER);           // soc_n users

  // negatives + final similarity
  topk_k<<<BATCH, T, 0, stream>>>(user_items, n_id, cand);
  sim_k<<<BATCH, 64, 0, stream>>>(bufCo, bufSoc, bufA, cand, walks, out);
}

// Round 4
// 1961.741 us; speedup vs baseline: 1.3077x; 1.3077x over previous
//
#include <hip/hip_runtime.h>
#include <hip/hip_fp16.h>
#include <stdint.h>

#define NUM_TOTAL 150000
#define NUM_USER  50000
#define NUM_ITEM  100000
#define E_SOC 1600000
#define E_CO  3200000
#define BATCH 512
#define MAX_UI 64
#define MAX_IU 50
#define NWALK 96
#define NCAND 11
#define MASKW 3125   // 100000/32

// modern JAX (jax_threefry_partitionable=True) — verified passing in round 2
#define TF_PARTITIONABLE 1

// ---------------- threefry2x32, key = (0, 42) ----------------
__device__ __forceinline__ uint32_t rotl32(uint32_t x, int r){ return (x<<r)|(x>>(32-r)); }

__device__ __forceinline__ void tf_core(uint32_t x0, uint32_t x1, uint32_t& o0, uint32_t& o1){
  const uint32_t k0 = 0u, k1 = 42u, k2 = 0u ^ 42u ^ 0x1BD11BDAu;
  x0 += k0; x1 += k1;
#define TF_R4(a,b,c,d) \
  x0+=x1; x1=rotl32(x1,a); x1^=x0; \
  x0+=x1; x1=rotl32(x1,b); x1^=x0; \
  x0+=x1; x1=rotl32(x1,c); x1^=x0; \
  x0+=x1; x1=rotl32(x1,d); x1^=x0;
  TF_R4(13,15,26,6)   x0+=k1; x1+=k2+1u;
  TF_R4(17,29,16,24)  x0+=k2; x1+=k0+2u;
  TF_R4(13,15,26,6)   x0+=k0; x1+=k1+3u;
  TF_R4(17,29,16,24)  x0+=k1; x1+=k2+4u;
  TF_R4(13,15,26,6)   x0+=k2; x1+=k0+5u;
#undef TF_R4
  o0 = x0; o1 = x1;
}

__device__ __forceinline__ uint32_t tf_bits(uint32_t j){
#if TF_PARTITIONABLE
  uint32_t o0, o1;
  tf_core(0u, j, o0, o1);
  return o0 ^ o1;
#else
  const uint32_t H = 25600000u;
  uint32_t o0, o1;
  if (j < H){ tf_core(j, j + H, o0, o1); return o0; }
  else      { tf_core(j - H, j, o0, o1); return o1; }
#endif
}

// ---------------- small utility kernels ----------------
__global__ void zero_i32(int* __restrict__ p, int n){
  int i = blockIdx.x*blockDim.x + threadIdx.x, st = gridDim.x*blockDim.x;
  for (; i<n; i+=st) p[i] = 0;
}

__global__ void hist_k(const int* __restrict__ dst, int E, int* __restrict__ cnt){
  int i = blockIdx.x*blockDim.x + threadIdx.x, st = gridDim.x*blockDim.x;
  for (; i<E; i+=st) atomicAdd(&cnt[dst[i]], 1);
}

// single-block exclusive scan: per-thread contiguous chunk + Hillis-Steele on partials
__global__ __launch_bounds__(1024) void exscan_k(const int* __restrict__ cnt, int n, int* __restrict__ off){
  __shared__ int part[1024];
  int tid = threadIdx.x;
  int chunk = (n + 1023) >> 10;
  int lo = tid*chunk;
  int hi = lo + chunk; if (hi > n) hi = n;
  int s = 0;
  for (int i=lo; i<hi; ++i) s += cnt[i];
  part[tid] = s; __syncthreads();
  for (int st=1; st<1024; st<<=1){
    int t = (tid>=st) ? part[tid-st] : 0;
    __syncthreads();
    part[tid] += t;
    __syncthreads();
  }
  int base = part[tid] - s;
  for (int i=lo; i<hi; ++i){ off[i] = base; base += cnt[i]; }
  if (tid == 1023) off[n] = part[1023];
}

__global__ void scatter_soc_k(const int* __restrict__ src, const int* __restrict__ dst,
                              const float* __restrict__ w, const int* __restrict__ off,
                              int* __restrict__ cur, int* __restrict__ srcS,
                              float* __restrict__ wS, int E){
  int i = blockIdx.x*blockDim.x + threadIdx.x, st = gridDim.x*blockDim.x;
  for (; i<E; i+=st){
    int d = dst[i];
    int p = off[d] + atomicAdd(&cur[d], 1);
    srcS[p] = src[i];
    wS[p]   = w[i];
  }
}

// co scatter: precompute per-edge weight dinv[src]*dinv[dst] so the agg loop
// reads a sequential f32 stream instead of a dependent random dinv gather.
__global__ void scatter_co_k(const int* __restrict__ src, const int* __restrict__ dst,
                             const float* __restrict__ dinv, const int* __restrict__ off,
                             int* __restrict__ cur, int* __restrict__ srcS,
                             float* __restrict__ wS, int E){
  int i = blockIdx.x*blockDim.x + threadIdx.x, st = gridDim.x*blockDim.x;
  for (; i<E; i+=st){
    int s = src[i], d = dst[i];
    int p = off[d] + atomicAdd(&cur[d], 1);
    srcS[p] = s;
    wS[p]   = dinv[s]*dinv[d];
  }
}

__global__ void dinv_k(const int* __restrict__ cnt, float* __restrict__ dinv, int n){
  int i = blockIdx.x*blockDim.x + threadIdx.x, st = gridDim.x*blockDim.x;
  for (; i<n; i+=st) dinv[i] = 1.0f / sqrtf((float)(cnt[i] + 1));   // deg = in-deg + self loop
}

// per-node softmax over incoming edge weights -> alpha (in place over wS)
__global__ void alpha_k(const int* __restrict__ off, float* __restrict__ wS, int n){
  int v = blockIdx.x*blockDim.x + threadIdx.x;
  if (v >= n) return;
  int e0 = off[v], e1 = off[v+1];
  if (e0 == e1) return;
  float m = -3.402823466e+38f;
  for (int e=e0; e<e1; ++e) m = fmaxf(m, wS[e]);
  float s = 0.f;
  for (int e=e0; e<e1; ++e) s += expf(wS[e] - m);
  float inv = 1.0f / (s + 1e-16f);
  for (int e=e0; e<e1; ++e) wS[e] = expf(wS[e] - m) * inv;
}

// f32 -> f16 (half2 per element pair)
__global__ void f2h_k(const float* __restrict__ in, __half2* __restrict__ out, int n2){
  int i = blockIdx.x*blockDim.x + threadIdx.x, st = gridDim.x*blockDim.x;
  for (; i<n2; i+=st){
    float2 f = ((const float2*)in)[i];
    out[i] = __float22half2_rn(f);
  }
}

// ---------------- aggregation: wave per dst node, f16 rows (half2/lane), 4-way MLP ----------------
__global__ void agg_h_k(const __half2* __restrict__ x, __half2* __restrict__ y,
                        const int* __restrict__ off, const int* __restrict__ srcS,
                        const float* __restrict__ wE, const float* __restrict__ dinv,
                        int n, int self){
  int gw = (blockIdx.x*blockDim.x + threadIdx.x) >> 6;
  int lane = threadIdx.x & 63;
  if (gw >= n) return;
  float ax = 0.f, ay = 0.f;
  if (self){
    float dv = dinv[gw];
    float2 f = __half22float2(x[(size_t)gw*64 + lane]);
    ax = dv*dv*f.x; ay = dv*dv*f.y;
  }
  int e1 = off[gw+1];
  int e  = off[gw];
  for (; e + 4 <= e1; e += 4){
    int s0 = srcS[e], s1 = srcS[e+1], s2 = srcS[e+2], s3 = srcS[e+3];
    float a0 = wE[e], a1 = wE[e+1], a2 = wE[e+2], a3 = wE[e+3];
    __half2 h0 = x[(size_t)s0*64 + lane];
    __half2 h1 = x[(size_t)s1*64 + lane];
    __half2 h2 = x[(size_t)s2*64 + lane];
    __half2 h3 = x[(size_t)s3*64 + lane];
    float2 f0 = __half22float2(h0), f1 = __half22float2(h1);
    float2 f2 = __half22float2(h2), f3 = __half22float2(h3);
    ax += a0*f0.x; ay += a0*f0.y;
    ax += a1*f1.x; ay += a1*f1.y;
    ax += a2*f2.x; ay += a2*f2.y;
    ax += a3*f3.x; ay += a3*f3.y;
  }
  for (; e < e1; ++e){
    int s = srcS[e]; float a = wE[e];
    float2 f = __half22float2(x[(size_t)s*64 + lane]);
    ax += a*f.x; ay += a*f.y;
  }
  y[(size_t)gw*64 + lane] = __float22half2_rn(make_float2(ax, ay));
}

// L2-normalize f16 rows in place (wave per row)
__global__ void norm_h_k(__half2* __restrict__ x, int n){
  int gw = (blockIdx.x*blockDim.x + threadIdx.x) >> 6;
  int lane = threadIdx.x & 63;
  if (gw >= n) return;
  __half2* p = x + (size_t)gw*64;
  float2 v = __half22float2(p[lane]);
  float ss = v.x*v.x + v.y*v.y;
  #pragma unroll
  for (int s=32; s; s>>=1) ss += __shfl_xor(ss, s, 64);
  float sc = 1.0f / fmaxf(sqrtf(ss), 1e-12f);
  p[lane] = __float22half2_rn(make_float2(v.x*sc, v.y*sc));
}

// anchor = mean of 50 unnormalized user rows, then L2-normalize (wave per item, 5-way MLP)
__global__ void anchor_h_k(const __half2* __restrict__ soc, const int* __restrict__ item_users,
                           __half2* __restrict__ outI, int n){
  int gw = (blockIdx.x*blockDim.x + threadIdx.x) >> 6;
  int lane = threadIdx.x & 63;
  if (gw >= n) return;
  const int* us = item_users + (size_t)gw*MAX_IU;
  float ax = 0.f, ay = 0.f;
  for (int k=0; k<MAX_IU; k+=5){
    int u0 = us[k], u1 = us[k+1], u2 = us[k+2], u3 = us[k+3], u4 = us[k+4];
    __half2 h0 = soc[(size_t)u0*64 + lane];
    __half2 h1 = soc[(size_t)u1*64 + lane];
    __half2 h2 = soc[(size_t)u2*64 + lane];
    __half2 h3 = soc[(size_t)u3*64 + lane];
    __half2 h4 = soc[(size_t)u4*64 + lane];
    float2 f0 = __half22float2(h0), f1 = __half22float2(h1), f2 = __half22float2(h2);
    float2 f3 = __half22float2(h3), f4 = __half22float2(h4);
    ax += f0.x + f1.x + f2.x + f3.x + f4.x;
    ay += f0.y + f1.y + f2.y + f3.y + f4.y;
  }
  const float inv = 1.0f / (50.0f + 1e-7f);
  ax *= inv; ay *= inv;
  float ss = ax*ax + ay*ay;
  #pragma unroll
  for (int s=32; s; s>>=1) ss += __shfl_xor(ss, s, 64);
  float sc = 1.0f / fmaxf(sqrtf(ss), 1e-12f);
  outI[(size_t)gw*64 + lane] = __float22half2_rn(make_float2(ax*sc, ay*sc));
}

// ---------------- top-k negative sampling (block per batch row) ----------------
__global__ __launch_bounds__(256) void topk_k(const int* __restrict__ user_items,
                                              const int* __restrict__ n_id,
                                              int* __restrict__ cand){
  __shared__ unsigned int mask[MASKW];
  __shared__ unsigned long long pool[2560];
  __shared__ unsigned long long red[256];
  int b = blockIdx.x, tid = threadIdx.x;
  for (int i=tid; i<MASKW; i+=256) mask[i] = 0u;
  __syncthreads();
  if (tid < MAX_UI){
    int it = user_items[b*MAX_UI + tid];
    if (it >= 0) atomicOr(&mask[it>>5], 1u << (it & 31));
  }
  __syncthreads();

  unsigned long long best[10];
  #pragma unroll
  for (int k=0; k<10; ++k) best[k] = 0ull;

  unsigned int jbase = (unsigned int)b * 100000u;
  for (int i=tid; i<NUM_ITEM; i+=256){
    if ((mask[i>>5] >> (i & 31)) & 1u) continue;
    unsigned int bits = tf_bits(jbase + (unsigned int)i);
    unsigned int v = bits >> 9;
    unsigned long long key = ((unsigned long long)v << 32) | (unsigned int)(~(unsigned int)i);
    if (key > best[9]){
      best[9] = key;
      #pragma unroll
      for (int r=9; r>0; --r)
        if (best[r] > best[r-1]){ unsigned long long t = best[r-1]; best[r-1] = best[r]; best[r] = t; }
    }
  }
  #pragma unroll
  for (int k=0; k<10; ++k) pool[tid*10 + k] = best[k];
  __syncthreads();

  for (int r=0; r<10; ++r){
    unsigned long long m = 0ull;
    #pragma unroll
    for (int k=0; k<10; ++k){ unsigned long long p = pool[tid*10 + k]; if (p > m) m = p; }
    red[tid] = m; __syncthreads();
    for (int s=128; s>0; s>>=1){
      if (tid < s && red[tid+s] > red[tid]) red[tid] = red[tid+s];
      __syncthreads();
    }
    unsigned long long win = red[0];
    if (tid == 0)
      cand[b*NCAND + 1 + r] = NUM_USER + (int)(~(unsigned int)(win & 0xffffffffull));
    #pragma unroll
    for (int k=0; k<10; ++k) if (pool[tid*10 + k] == win) pool[tid*10 + k] = 0ull;
    __syncthreads();
  }
  if (tid == 0) cand[b*NCAND] = n_id[b*2 + 1];   // positive item (global id)
}

// ---------------- similarity (mean over walks collapses to one dot), f16 rows ----------------
__global__ void sim_h_k(const __half2* __restrict__ coN, const __half2* __restrict__ socU,
                        const __half2* __restrict__ socI, const int* __restrict__ cand,
                        const int* __restrict__ walks, float* __restrict__ out){
  int b = blockIdx.x;
  int lane = threadIdx.x;   // 64 threads
  float scx=0.f, scy=0.f, ssx=0.f, ssy=0.f;
  for (int w=0; w<NWALK; w+=4){
    int i0 = walks[b*NWALK + w],   i1 = walks[b*NWALK + w+1];
    int i2 = walks[b*NWALK + w+2], i3 = walks[b*NWALK + w+3];
    __half2 c0 = coN[(size_t)i0*64 + lane], c1 = coN[(size_t)i1*64 + lane];
    __half2 c2 = coN[(size_t)i2*64 + lane], c3 = coN[(size_t)i3*64 + lane];
    const __half2* p0 = (i0 < NUM_USER) ? socU + (size_t)i0*64 : socI + (size_t)(i0-NUM_USER)*64;
    const __half2* p1 = (i1 < NUM_USER) ? socU + (size_t)i1*64 : socI + (size_t)(i1-NUM_USER)*64;
    const __half2* p2 = (i2 < NUM_USER) ? socU + (size_t)i2*64 : socI + (size_t)(i2-NUM_USER)*64;
    const __half2* p3 = (i3 < NUM_USER) ? socU + (size_t)i3*64 : socI + (size_t)(i3-NUM_USER)*64;
    __half2 s0 = p0[lane], s1 = p1[lane], s2 = p2[lane], s3 = p3[lane];
    float2 fc0 = __half22float2(c0), fc1 = __half22float2(c1);
    float2 fc2 = __half22float2(c2), fc3 = __half22float2(c3);
    float2 fs0 = __half22float2(s0), fs1 = __half22float2(s1);
    float2 fs2 = __half22float2(s2), fs3 = __half22float2(s3);
    scx += fc0.x + fc1.x + fc2.x + fc3.x;
    scy += fc0.y + fc1.y + fc2.y + fc3.y;
    ssx += fs0.x + fs1.x + fs2.x + fs3.x;
    ssy += fs0.y + fs1.y + fs2.y + fs3.y;
  }
  for (int c=0; c<NCAND; ++c){
    int idx = cand[b*NCAND + c];                 // always in [NUM_USER, NUM_TOTAL)
    float2 cv = __half22float2(coN[(size_t)idx*64 + lane]);
    float2 sv = __half22float2(socI[(size_t)(idx - NUM_USER)*64 + lane]);
    float dco = cv.x*scx + cv.y*scy;
    float dso = sv.x*ssx + sv.y*ssy;
    #pragma unroll
    for (int s=32; s; s>>=1){
      dco += __shfl_xor(dco, s, 64);
      dso += __shfl_xor(dso, s, 64);
    }
    if (lane == 0){
      float com = 0.5f + 0.5f*(dco / 96.0f);
      float som = 0.5f + 0.5f*(dso / 96.0f);
      out[b*NCAND + c] = 0.7f*com + 0.3f*som;
    }
  }
}

// ---------------- host ----------------
extern "C" void kernel_launch(void* const* d_in, const int* in_sizes, int n_in,
                              void* d_out, int out_size, void* d_ws, size_t ws_size,
                              hipStream_t stream){
  (void)in_sizes; (void)n_in; (void)out_size; (void)ws_size;
  const float* id_emb     = (const float*)d_in[0];
  const float* soc_id_emb = (const float*)d_in[1];
  const float* soc_w      = (const float*)d_in[2];
  const int*   soc_ei     = (const int*)d_in[3];   // [0:E) src, [E:2E) dst
  const int*   co_ei      = (const int*)d_in[4];
  const int*   n_id       = (const int*)d_in[5];
  const int*   user_items = (const int*)d_in[6];
  const int*   item_users = (const int*)d_in[7];
  const int*   walks      = (const int*)d_in[8];
  float* out = (float*)d_out;

  // workspace layout (~256 MB)
  char* w = (char*)d_ws;
  size_t cur = 0;
  auto take = [&](size_t bytes)->void*{
    void* p = w + cur;
    cur = (cur + bytes + 255) & ~(size_t)255;
    return p;
  };
  __half2* socId16 = (__half2*)take((size_t)NUM_TOTAL*64*4);   // f16 soc_id_emb
  __half2* id16    = (__half2*)take((size_t)NUM_TOTAL*64*4);   // f16 id_emb
  __half2* t16     = (__half2*)take((size_t)NUM_TOTAL*64*4);   // ping buffer (layer-1 out)
  __half2* soc16   = (__half2*)take((size_t)NUM_TOTAL*64*4);   // soc_emb (users normalized later)
  __half2* co16    = (__half2*)take((size_t)NUM_TOTAL*64*4);   // co_emb -> co_n in place
  __half2* anch16  = (__half2*)take((size_t)NUM_ITEM*64*4);    // normalized anchors
  int*   socOff  = (int*)take((size_t)(NUM_TOTAL+1)*4);
  int*   coOff   = (int*)take((size_t)(NUM_TOTAL+1)*4);
  int*   cntS    = (int*)take((size_t)NUM_TOTAL*4);
  int*   cntC    = (int*)take((size_t)NUM_TOTAL*4);
  int*   cur2    = (int*)take((size_t)NUM_TOTAL*4);
  float* dinv    = (float*)take((size_t)NUM_TOTAL*4);
  int*   socSrcS = (int*)take((size_t)E_SOC*4);
  float* socWS   = (float*)take((size_t)E_SOC*4);
  int*   coSrcS  = (int*)take((size_t)E_CO*4);
  float* coWS    = (float*)take((size_t)E_CO*4);
  int*   cand    = (int*)take((size_t)BATCH*NCAND*4);

  const int T = 256;
  // CSC build
  zero_i32<<<512, T, 0, stream>>>(cntS, NUM_TOTAL);
  zero_i32<<<512, T, 0, stream>>>(cntC, NUM_TOTAL);
  hist_k<<<2048, T, 0, stream>>>(soc_ei + E_SOC, E_SOC, cntS);
  hist_k<<<2048, T, 0, stream>>>(co_ei + E_CO,  E_CO,  cntC);
  exscan_k<<<1, 1024, 0, stream>>>(cntS, NUM_TOTAL, socOff);
  exscan_k<<<1, 1024, 0, stream>>>(cntC, NUM_TOTAL, coOff);
  dinv_k<<<(NUM_TOTAL + T - 1)/T, T, 0, stream>>>(cntC, dinv, NUM_TOTAL);
  zero_i32<<<512, T, 0, stream>>>(cur2, NUM_TOTAL);
  scatter_soc_k<<<2048, T, 0, stream>>>(soc_ei, soc_ei + E_SOC, soc_w, socOff, cur2, socSrcS, socWS, E_SOC);
  zero_i32<<<512, T, 0, stream>>>(cur2, NUM_TOTAL);
  scatter_co_k<<<2048, T, 0, stream>>>(co_ei, co_ei + E_CO, dinv, coOff, cur2, coSrcS, coWS, E_CO);
  alpha_k<<<(NUM_TOTAL + T - 1)/T, T, 0, stream>>>(socOff, socWS, NUM_TOTAL);

  // f32 -> f16 embedding tables
  f2h_k<<<2048, T, 0, stream>>>(soc_id_emb, socId16, NUM_TOTAL*64);
  f2h_k<<<2048, T, 0, stream>>>(id_emb,     id16,    NUM_TOTAL*64);

  // graph convolutions (wave per node, f16 gathers, f32 accum)
  int aggGrid = (NUM_TOTAL + 3) / 4;
  agg_h_k<<<aggGrid, T, 0, stream>>>(socId16, t16,   socOff, socSrcS, socWS, dinv, NUM_TOTAL, 0);
  agg_h_k<<<aggGrid, T, 0, stream>>>(t16,     soc16, socOff, socSrcS, socWS, dinv, NUM_TOTAL, 0);
  agg_h_k<<<aggGrid, T, 0, stream>>>(id16,    t16,   coOff,  coSrcS,  coWS,  dinv, NUM_TOTAL, 1);
  agg_h_k<<<aggGrid, T, 0, stream>>>(t16,     co16,  coOff,  coSrcS,  coWS,  dinv, NUM_TOTAL, 1);

  // normalizations / anchors (anchor reads UNnormalized soc rows, so it runs first)
  norm_h_k<<<aggGrid, T, 0, stream>>>(co16, NUM_TOTAL);                              // co_n
  anchor_h_k<<<(NUM_ITEM + 3)/4, T, 0, stream>>>(soc16, item_users, anch16, NUM_ITEM);
  norm_h_k<<<(NUM_USER + 3)/4, T, 0, stream>>>(soc16, NUM_USER);                     // soc_n users

  // negatives + final similarity
  topk_k<<<BATCH, T, 0, stream>>>(user_items, n_id, cand);
  sim_h_k<<<BATCH, 64, 0, stream>>>(co16, soc16, anch16, cand, walks, out);
}